// Round 5
// baseline (3137.265 us; speedup 1.0000x reference)
//
#include <hip/hip_runtime.h>
#include <math.h>

#define EMBD 128
#define HIDD 128
#define NTAR 16
#define BSEQ 4096
#define G4   512
#define CH   8            // zx prefetch / hs store-batch chunk

typedef float v2f __attribute__((ext_vector_type(2)));

// Butterfly add over lane bits 0..2 (the kq k-group index), on the VALU
// pipe via DPP — replaces the LDS partial array + its barrier entirely.
// 0xB1 = quad_perm[1,0,3,2] (xor1), 0x4E = quad_perm[2,3,0,1] (xor2),
// 0x141 = row_half_mirror (lane^7; valid as xor4 AFTER xor1+xor2 have
// equalized each quad).
#define DPP_ADD(x, ctrl)                                                     \
    ((x) + __int_as_float(__builtin_amdgcn_update_dpp(                       \
               0, __float_as_int(x), (ctrl), 0xf, 0xf, true)))

__device__ __forceinline__ float fast_sigmoid(float z) {
    return __builtin_amdgcn_rcpf(1.f + __expf(-z));
}
__device__ __forceinline__ float fast_tanh(float z) {
    return 1.f - 2.f * __builtin_amdgcn_rcpf(1.f + __expf(2.f * z));
}

// ---------------------------------------------------------------------------
// Kernel 1: input projection, transposed layout.
// zxT[(t*128 + u)*4 + g] = dot(emb[x[t]], w_ih[g*128+u]) + b_ih + b_hh
// ---------------------------------------------------------------------------
__global__ void input_proj_kernel(const int* __restrict__ x,
                                  const float* __restrict__ emb,
                                  const float* __restrict__ w_ih,
                                  const float* __restrict__ b_ih,
                                  const float* __restrict__ b_hh,
                                  float* __restrict__ zxT) {
    const int t = blockIdx.x;
    const int j = threadIdx.x;            // 0..511
    const int u = j >> 2;
    const int g = j & 3;
    const int row = g * HIDD + u;
    const int idx = x[t];
    const float4* __restrict__ er = (const float4*)(emb + (long long)idx * EMBD);
    const float4* __restrict__ wr = (const float4*)(w_ih + row * EMBD);
    float acc = 0.f;
#pragma unroll
    for (int k = 0; k < EMBD / 4; ++k) {
        float4 e = er[k];
        float4 w = wr[k];
        acc += e.x * w.x + e.y * w.y + e.z * w.z + e.w * w.w;
    }
    zxT[(t * HIDD + u) * 4 + g] = acc + b_ih[row] + b_hh[row];
}

// ---------------------------------------------------------------------------
// Kernel 2: sequential LSTM. One workgroup, 512 threads (8 waves, 2/SIMD).
//
// Thread coords: lane l = tid&63, wave wv = tid>>6; kq = l&7 (k-group,
// cols [16kq,16kq+16)), rg = l>>3. Thread computes partial dots for the 8
// gate-rows {wv*64 + rg*8 + m} over its 16-col slice (8x8 v2f weights,
// 128 VGPRs, pinned; on gfx950 these may legally live in AGPRs — pk-FMA
// reads AGPR operands directly, so a low arch-VGPR count is fine).
//
// Per step:  4x ds_read_b128 of the wave's h-slices -> 64 pk_fma ->
// 3-round DPP butterfly over kq (VALU, no LDS/barrier) -> every lane
// holds complete z for row rowBase+kq -> add prefetched zx -> this
// wave's gate transcendental (spread over ALL 8 waves) -> one stride-1
// b32 write to a_sh.  Barrier.  Phase C (tid<128): 4 b32 reads, c/h
// update (1 tanh), write h_sh + hreg.  Barrier.
//
// zx is loaded per-thread (its own row) one CH-chunk ahead; hs stores are
// batched per chunk — so the vmcnt(0) drain at each __syncthreads only
// ever sees loads/stores issued a full chunk (~6000 cyc) earlier.
// ---------------------------------------------------------------------------
__global__ __launch_bounds__(512, 1)
void lstm_seq_kernel(const float* __restrict__ zxT,
                     const float* __restrict__ w_hh,
                     float* __restrict__ hs) {
    __shared__ float h_sh[HIDD];
    __shared__ float a_sh[G4];

    const int tid = threadIdx.x;
    const int l   = tid & 63;
    const int wv  = tid >> 6;
    const int kq  = l & 7;               // k-group
    const int rg  = l >> 3;
    const int rowBase = wv * 64 + rg * 8;
    const int myRow   = rowBase + kq;    // row this lane owns post-butterfly
    const int u       = myRow & 127;
    const int gate    = myRow >> 7;      // == wv>>1, wave-uniform
    const int aaddr   = gate * HIDD + u; // lanes stride-1 -> conflict-free
    const bool g_tanh = (gate == 2);

    // Weights: w2[m][k2] = W_hh[rowBase+m][16*kq + 2*k2 .. +1]
    v2f w2[8][8];
#pragma unroll
    for (int m = 0; m < 8; ++m) {
        const float4* __restrict__ wr =
            (const float4*)(w_hh + (rowBase + m) * HIDD + 16 * kq);
#pragma unroll
        for (int k4 = 0; k4 < 4; ++k4) {
            float4 v = wr[k4];
            w2[m][2 * k4 + 0] = (v2f){v.x, v.y};
            w2[m][2 * k4 + 1] = (v2f){v.z, v.w};
        }
    }
#pragma unroll
    for (int m = 0; m < 8; ++m)
#pragma unroll
        for (int k = 0; k < 8; ++k)
            asm volatile("" : "+v"(w2[m][k]));   // no rematerialization

    if (tid < HIDD) h_sh[tid] = 0.f;
    float c = 0.f;
    float hreg[CH];
    float zcur[CH], zfut[CH];
#pragma unroll
    for (int s = 0; s < CH; ++s) {       // chunk 0 zx preload (own row)
        zcur[s] = zxT[(s * HIDD + u) * 4 + gate];
        hreg[s] = 0.f;
    }
    __syncthreads();

    const float4* hq = (const float4*)h_sh + 4 * kq;  // this lane's h slice

    for (int tc = 0; tc < BSEQ; tc += CH) {
        // Batch-store previous chunk's h (acks drain ~1 chunk later).
        if (tid < HIDD && tc > 0) {
#pragma unroll
            for (int s = 0; s < CH; ++s)
                hs[(tc - CH + s) * HIDD + tid] = hreg[s];
        }
        // Prefetch NEXT chunk's zx (full chunk of latency hiding).
        {
            const int tn = (tc + CH < BSEQ) ? (tc + CH) : (BSEQ - CH);
#pragma unroll
            for (int s = 0; s < CH; ++s)
                zfut[s] = zxT[((tn + s) * HIDD + u) * 4 + gate];
        }

#pragma unroll
        for (int s = 0; s < CH; ++s) {
            // h slice: 4 b128 reads (8 distinct addresses/wave, broadcast x8).
            const float4 h0 = hq[0], h1 = hq[1], h2 = hq[2], h3 = hq[3];
            v2f hp[8];
            hp[0] = (v2f){h0.x, h0.y}; hp[1] = (v2f){h0.z, h0.w};
            hp[2] = (v2f){h1.x, h1.y}; hp[3] = (v2f){h1.z, h1.w};
            hp[4] = (v2f){h2.x, h2.y}; hp[5] = (v2f){h2.z, h2.w};
            hp[6] = (v2f){h3.x, h3.y}; hp[7] = (v2f){h3.z, h3.w};

            float zsel = 0.f;
#pragma unroll
            for (int m = 0; m < 8; ++m) {
                v2f a = (v2f){0.f, 0.f};
#pragma unroll
                for (int k = 0; k < 8; ++k)
                    a += hp[k] * w2[m][k];        // v_pk_fma_f32
                float p = a.x + a.y;
                p = DPP_ADD(p, 0xB1);             // xor1
                p = DPP_ADD(p, 0x4E);             // xor2
                p = DPP_ADD(p, 0x141);            // xor4 (half-mirror)
                zsel = (kq == m) ? p : zsel;      // cndmask, no dyn index
            }
            const float z = zsel + zcur[s];
            const float act = g_tanh ? fast_tanh(z) : fast_sigmoid(z);
            a_sh[aaddr] = act;
            __syncthreads();

            // Phase C: tiny serial tail (1 tanh + 3 fma on 2 waves).
            if (tid < HIDD) {
                const float gi = a_sh[tid];
                const float gf = a_sh[HIDD + tid];
                const float gg = a_sh[2 * HIDD + tid];
                const float go = a_sh[3 * HIDD + tid];
                c = gf * c + gi * gg;
                const float h = go * fast_tanh(c);
                h_sh[tid] = h;
                hreg[s] = h;
            }
            __syncthreads();
        }
#pragma unroll
        for (int s = 0; s < CH; ++s) zcur[s] = zfut[s];
    }
    if (tid < HIDD) {
#pragma unroll
        for (int s = 0; s < CH; ++s)
            hs[(BSEQ - CH + s) * HIDD + tid] = hreg[s];
    }
}

// ---------------------------------------------------------------------------
// Kernel 3: final FC. out[t][n] = dot(hs[t], w_fc[n]) + b_fc[n].
// ---------------------------------------------------------------------------
__global__ void fc_kernel(const float* __restrict__ hs,
                          const float* __restrict__ w_fc,
                          const float* __restrict__ b_fc,
                          float* __restrict__ out) {
    const int gid = blockIdx.x * blockDim.x + threadIdx.x;
    if (gid >= BSEQ * NTAR) return;
    const int n = gid & (NTAR - 1);
    const int t = gid >> 4;
    const float4* __restrict__ hr = (const float4*)(hs + t * HIDD);
    const float4* __restrict__ wr = (const float4*)(w_fc + n * HIDD);
    float acc = 0.f;
#pragma unroll
    for (int k = 0; k < HIDD / 4; ++k) {
        float4 h = hr[k];
        float4 wv = wr[k];
        acc += h.x * wv.x + h.y * wv.y + h.z * wv.z + h.w * wv.w;
    }
    out[gid] = acc + b_fc[n];
}

// ---------------------------------------------------------------------------
extern "C" void kernel_launch(void* const* d_in, const int* in_sizes, int n_in,
                              void* d_out, int out_size, void* d_ws, size_t ws_size,
                              hipStream_t stream) {
    const int*   x    = (const int*)d_in[0];
    const float* emb  = (const float*)d_in[1];
    const float* w_ih = (const float*)d_in[2];
    const float* w_hh = (const float*)d_in[3];
    const float* b_ih = (const float*)d_in[4];
    const float* b_hh = (const float*)d_in[5];
    const float* w_fc = (const float*)d_in[6];
    const float* b_fc = (const float*)d_in[7];
    float* out = (float*)d_out;

    // Workspace: zxT (4096*512 f32 = 8 MB) | hs (4096*128 f32 = 2 MB)
    float* zxT = (float*)d_ws;
    float* hs  = zxT + (size_t)BSEQ * G4;

    input_proj_kernel<<<BSEQ, G4, 0, stream>>>(x, emb, w_ih, b_ih, b_hh, zxT);
    lstm_seq_kernel<<<1, 512, 0, stream>>>(zxT, w_hh, hs);
    fc_kernel<<<(BSEQ * NTAR + 255) / 256, 256, 0, stream>>>(hs, w_fc, b_fc, out);
}

// Round 6
// 2536.033 us; speedup vs baseline: 1.2371x; 1.2371x over previous
//
#include <hip/hip_runtime.h>
#include <math.h>

#define EMBD 128
#define HIDD 128
#define NTAR 16
#define BSEQ 4096
#define G4   512
#define CH   8            // zx load / hs store batch (amortizes barrier vmcnt drain)

typedef float v2f __attribute__((ext_vector_type(2)));

// Quad-lane butterfly add on the VALU pipe (quad_perm DPP, validated R5):
// 0xB1 = [1,0,3,2] (xor1), 0x4E = [2,3,0,1] (xor2).
#define DPP_ADD(x, ctrl)                                                     \
    ((x) + __int_as_float(__builtin_amdgcn_update_dpp(                       \
               0, __float_as_int(x), (ctrl), 0xf, 0xf, true)))

__device__ __forceinline__ float fast_sigmoid(float z) {
    return __builtin_amdgcn_rcpf(1.f + __expf(-z));
}
__device__ __forceinline__ float fast_tanh(float z) {
    return 1.f - 2.f * __builtin_amdgcn_rcpf(1.f + __expf(2.f * z));
}

// ---------------------------------------------------------------------------
// Kernel 1: input projection, transposed layout.
// zxT[(t*128 + u)*4 + g] = dot(emb[x[t]], w_ih[g*128+u]) + b_ih + b_hh
// so the LSTM reads one float4 (all 4 gates of unit u) per thread per step.
// ---------------------------------------------------------------------------
__global__ void input_proj_kernel(const int* __restrict__ x,
                                  const float* __restrict__ emb,
                                  const float* __restrict__ w_ih,
                                  const float* __restrict__ b_ih,
                                  const float* __restrict__ b_hh,
                                  float* __restrict__ zxT) {
    const int t = blockIdx.x;
    const int j = threadIdx.x;            // 0..511
    const int u = j >> 2;
    const int g = j & 3;
    const int row = g * HIDD + u;
    const int idx = x[t];
    const float4* __restrict__ er = (const float4*)(emb + (long long)idx * EMBD);
    const float4* __restrict__ wr = (const float4*)(w_ih + row * EMBD);
    float acc = 0.f;
#pragma unroll
    for (int k = 0; k < EMBD / 4; ++k) {
        float4 e = er[k];
        float4 w = wr[k];
        acc += e.x * w.x + e.y * w.y + e.z * w.z + e.w * w.w;
    }
    zxT[(t * HIDD + u) * 4 + g] = acc + b_ih[row] + b_hh[row];
}

// ---------------------------------------------------------------------------
// Kernel 2: sequential LSTM. 512 threads (8 waves, 2/SIMD), ONE barrier/step.
//
// Lane layout: l=tid&63, wv=tid>>6; unit u = wv*16 + (l>>2); k-quarter
// kq = l&3 (cols [32kq,32kq+32)). Thread computes partials of ALL 4 gate
// rows {u+128g} over its quarter (64 v2f weights, pinned; the allocator
// parks long-lived pinned values in the unified AGPR file — low reported
// VGPR_Count with resident weights, per R4/R5 evidence).
//
// Per step: 8x ds_read_b128 of the h quarter in ROTATED column order
// ((4k4+8kq)&31; weights loaded to match) -> the 4 distinct addresses per
// read hit 4 disjoint bank groups: zero conflicts (R5's 128/step 4-way
// conflict fix, at zero runtime cost). 64 pk_fma -> per-gate quad
// butterfly (2 DPP rounds) -> every lane has all 4 z's for its unit ->
// in-lane gates + c/h update, 4-fold redundant across quad lanes, spread
// over ALL waves (no serial phase-C, no a_sh round-trip). kq==0 lanes
// write h to the OTHER h_db buffer (double-buffer kills the WAR hazard
// that forced R4/R5's second barrier).
// ---------------------------------------------------------------------------
__global__ __launch_bounds__(512, 2)
void lstm_seq_kernel(const float* __restrict__ zxT,
                     const float* __restrict__ w_hh,
                     float* __restrict__ hs) {
    __shared__ float h_db[2][HIDD];

    const int tid = threadIdx.x;
    const int l   = tid & 63;
    const int wv  = tid >> 6;
    const int kq  = l & 3;               // k-quarter
    const int us  = l >> 2;              // unit-sub 0..15
    const int u   = wv * 16 + us;        // hidden unit 0..127
    const bool writer = (kq == 0);

    // Weights in ROTATED column order: position k4 covers absolute columns
    // 32*kq + ((4*k4 + 8*kq)&31) + {0..3}, matching the h read order below.
    v2f w2[4][16];
#pragma unroll
    for (int g = 0; g < 4; ++g) {
        const float* __restrict__ wr = w_hh + (g * HIDD + u) * HIDD;
#pragma unroll
        for (int k4 = 0; k4 < 8; ++k4) {
            const int c0 = 32 * kq + ((4 * k4 + 8 * kq) & 31);
            float4 v = *(const float4*)(wr + c0);
            w2[g][2 * k4 + 0] = (v2f){v.x, v.y};
            w2[g][2 * k4 + 1] = (v2f){v.z, v.w};
        }
    }
#pragma unroll
    for (int g = 0; g < 4; ++g)
#pragma unroll
        for (int k = 0; k < 16; ++k)
            asm volatile("" : "+v"(w2[g][k]));   // no rematerialization

    if (tid < HIDD) { h_db[0][tid] = 0.f; h_db[1][tid] = 0.f; }
    float c = 0.f;
    float hreg[CH];
    float4 zcur[CH];
#pragma unroll
    for (int s = 0; s < CH; ++s) hreg[s] = 0.f;

    const float4* __restrict__ zx4 = (const float4*)zxT;
    __syncthreads();

    for (int tc = 0; tc < BSEQ; tc += CH) {
        // Batch-store previous chunk's h (one lane per unit, coalesced 64B/wave).
        if (writer && tc > 0) {
#pragma unroll
            for (int s = 0; s < CH; ++s)
                hs[(tc - CH + s) * HIDD + u] = hreg[s];
        }
        // Load this chunk's zx rows (drained at the first in-chunk barrier;
        // one exposed HBM stall per chunk).
#pragma unroll
        for (int s = 0; s < CH; ++s)
            zcur[s] = zx4[(tc + s) * HIDD + u];

#pragma unroll
        for (int s = 0; s < CH; ++s) {
            // t = tc + s; tc is a multiple of 8 so t&1 == s&1: compile-time
            // buffer parity per unrolled body -> LDS addresses hoisted.
            const float* __restrict__ rb = h_db[s & 1];
            const int    wb             = (s & 1) ^ 1;

            // h quarter, rotated order, conflict-free (4 disjoint bank groups).
            float4 hv[8];
#pragma unroll
            for (int k4 = 0; k4 < 8; ++k4) {
                const int c0 = 32 * kq + ((4 * k4 + 8 * kq) & 31);
                hv[k4] = *(const float4*)(rb + c0);
            }

            v2f a[4] = {(v2f){0.f,0.f},(v2f){0.f,0.f},(v2f){0.f,0.f},(v2f){0.f,0.f}};
#pragma unroll
            for (int k4 = 0; k4 < 8; ++k4) {
                const v2f hlo = (v2f){hv[k4].x, hv[k4].y};
                const v2f hhi = (v2f){hv[k4].z, hv[k4].w};
#pragma unroll
                for (int g = 0; g < 4; ++g) {
                    a[g] += hlo * w2[g][2 * k4 + 0];   // v_pk_fma_f32
                    a[g] += hhi * w2[g][2 * k4 + 1];
                }
            }

            // Quad butterfly: all 4 lanes end with complete z per gate.
            float z0 = a[0].x + a[0].y, z1 = a[1].x + a[1].y;
            float z2 = a[2].x + a[2].y, z3 = a[3].x + a[3].y;
            z0 = DPP_ADD(z0, 0xB1); z0 = DPP_ADD(z0, 0x4E);
            z1 = DPP_ADD(z1, 0xB1); z1 = DPP_ADD(z1, 0x4E);
            z2 = DPP_ADD(z2, 0xB1); z2 = DPP_ADD(z2, 0x4E);
            z3 = DPP_ADD(z3, 0xB1); z3 = DPP_ADD(z3, 0x4E);

            const float4 zb = zcur[s];
            const float gi = fast_sigmoid(z0 + zb.x);
            const float gf = fast_sigmoid(z1 + zb.y);
            const float gg = fast_tanh   (z2 + zb.z);
            const float go = fast_sigmoid(z3 + zb.w);
            c = gf * c + gi * gg;                  // replicated x4: identical
            const float h = go * fast_tanh(c);
            hreg[s] = h;
            if (writer) h_db[wb][u] = h;           // 16 contiguous floats/wave
            __syncthreads();                       // THE one barrier per step
        }
    }
    if (writer) {
#pragma unroll
        for (int s = 0; s < CH; ++s)
            hs[(BSEQ - CH + s) * HIDD + u] = hreg[s];
    }
}

// ---------------------------------------------------------------------------
// Kernel 3: final FC. out[t][n] = dot(hs[t], w_fc[n]) + b_fc[n].
// ---------------------------------------------------------------------------
__global__ void fc_kernel(const float* __restrict__ hs,
                          const float* __restrict__ w_fc,
                          const float* __restrict__ b_fc,
                          float* __restrict__ out) {
    const int gid = blockIdx.x * blockDim.x + threadIdx.x;
    if (gid >= BSEQ * NTAR) return;
    const int n = gid & (NTAR - 1);
    const int t = gid >> 4;
    const float4* __restrict__ hr = (const float4*)(hs + t * HIDD);
    const float4* __restrict__ wr = (const float4*)(w_fc + n * HIDD);
    float acc = 0.f;
#pragma unroll
    for (int k = 0; k < HIDD / 4; ++k) {
        float4 h = hr[k];
        float4 wv = wr[k];
        acc += h.x * wv.x + h.y * wv.y + h.z * wv.z + h.w * wv.w;
    }
    out[gid] = acc + b_fc[n];
}

// ---------------------------------------------------------------------------
extern "C" void kernel_launch(void* const* d_in, const int* in_sizes, int n_in,
                              void* d_out, int out_size, void* d_ws, size_t ws_size,
                              hipStream_t stream) {
    const int*   x    = (const int*)d_in[0];
    const float* emb  = (const float*)d_in[1];
    const float* w_ih = (const float*)d_in[2];
    const float* w_hh = (const float*)d_in[3];
    const float* b_ih = (const float*)d_in[4];
    const float* b_hh = (const float*)d_in[5];
    const float* w_fc = (const float*)d_in[6];
    const float* b_fc = (const float*)d_in[7];
    float* out = (float*)d_out;

    // Workspace: zxT (4096*512 f32 = 8 MB) | hs (4096*128 f32 = 2 MB)
    float* zxT = (float*)d_ws;
    float* hs  = zxT + (size_t)BSEQ * G4;

    input_proj_kernel<<<BSEQ, G4, 0, stream>>>(x, emb, w_ih, b_ih, b_hh, zxT);
    lstm_seq_kernel<<<1, 512, 0, stream>>>(zxT, w_hh, hs);
    fc_kernel<<<(BSEQ * NTAR + 255) / 256, 256, 0, stream>>>(hs, w_fc, b_fc, out);
}

// Round 8
// 2439.176 us; speedup vs baseline: 1.2862x; 1.0397x over previous
//
#include <hip/hip_runtime.h>
#include <math.h>

#define EMBD 128
#define HIDD 128
#define NTAR 16
#define BSEQ 4096
#define G4   512
#define CH   8            // zx load / hs store batch (amortizes barrier vmcnt drain)

typedef _Float16 v2h __attribute__((ext_vector_type(2)));

// Quad-lane butterfly add on the VALU pipe (quad_perm DPP, validated R5/R6):
// 0xB1 = [1,0,3,2] (xor1), 0x4E = [2,3,0,1] (xor2).
#define DPP_ADD(x, ctrl)                                                     \
    ((x) + __int_as_float(__builtin_amdgcn_update_dpp(                       \
               0, __float_as_int(x), (ctrl), 0xf, 0xf, true)))

__device__ __forceinline__ float fast_sigmoid(float z) {
    return __builtin_amdgcn_rcpf(1.f + __expf(-z));
}
__device__ __forceinline__ float fast_tanh(float z) {
    return 1.f - 2.f * __builtin_amdgcn_rcpf(1.f + __expf(2.f * z));
}

// f32 pair -> packed f16 (RTZ), bit-cast to our v2h element type.
__device__ __forceinline__ v2h pack_f16(float f0, float f1) {
    return __builtin_bit_cast(v2h, __builtin_amdgcn_cvt_pkrtz(f0, f1));
}

// ---------------------------------------------------------------------------
// Kernel 1: input projection, transposed layout (fp32 — zx precision anchor).
// zxT[(t*128 + u)*4 + g] = dot(emb[x[t]], w_ih[g*128+u]) + b_ih + b_hh
// ---------------------------------------------------------------------------
__global__ void input_proj_kernel(const int* __restrict__ x,
                                  const float* __restrict__ emb,
                                  const float* __restrict__ w_ih,
                                  const float* __restrict__ b_ih,
                                  const float* __restrict__ b_hh,
                                  float* __restrict__ zxT) {
    const int t = blockIdx.x;
    const int j = threadIdx.x;            // 0..511
    const int u = j >> 2;
    const int g = j & 3;
    const int row = g * HIDD + u;
    const int idx = x[t];
    const float4* __restrict__ er = (const float4*)(emb + (long long)idx * EMBD);
    const float4* __restrict__ wr = (const float4*)(w_ih + row * EMBD);
    float acc = 0.f;
#pragma unroll
    for (int k = 0; k < EMBD / 4; ++k) {
        float4 e = er[k];
        float4 w = wr[k];
        acc += e.x * w.x + e.y * w.y + e.z * w.z + e.w * w.w;
    }
    zxT[(t * HIDD + u) * 4 + g] = acc + b_ih[row] + b_hh[row];
}

// ---------------------------------------------------------------------------
// Kernel 2: sequential LSTM. 512 threads (8 waves, 2/SIMD), one barrier/step.
//
// R6 post-mortem: fp32-FMA-issue-bound (v_pk_fma_f32 is HALF-rate; 512
// cyc/SIMD/step of FMA issue). Fix: v_dot2_f32_f16 — 2 f16 MACs/lane at
// FULL rate (fp16 vector = 2x fp32 peak), f32 accumulate. W_hh and the h
// broadcast are f16; c, zx, hs stay fp32.
//
// Lane layout (as R6): unit u = wv*16 + (l>>2), k-quarter kq = l&3
// (cols [32kq,32kq+32)). Per thread: 64 half2 weights (4 gates x 16),
// pinned; 4x ds_read_b128 of the f16 h-quarter in rotated chunk order
// cj=(j+kq)&3 (per-instruction bank groups {16kq/2+4cj mod 32} disjoint ->
// conflict-free); 64 fdot2 -> 2-round quad DPP butterfly -> in-lane
// gates + c/h update (x4 redundant, all waves); kq==0 lane converts h to
// f16, writes the other h_db buffer (double-buffer = no WAR barrier).
// ---------------------------------------------------------------------------
__global__ __launch_bounds__(512, 2)
void lstm_seq_kernel(const float* __restrict__ zxT,
                     const float* __restrict__ w_hh,
                     float* __restrict__ hs) {
    __shared__ __align__(16) _Float16 h_db[2][HIDD];

    const int tid = threadIdx.x;
    const int l   = tid & 63;
    const int wv  = tid >> 6;
    const int kq  = l & 3;               // k-quarter
    const int us  = l >> 2;              // unit-sub 0..15
    const int u   = wv * 16 + us;        // hidden unit 0..127
    const bool writer = (kq == 0);

    // Weights as half2, chunk-rotated to match the h read order below:
    // w2h[g][4*j + p] covers cols 32kq + 8*((j+kq)&3) + 2p .. +1.
    v2h w2h[4][16];
#pragma unroll
    for (int g = 0; g < 4; ++g) {
        const float* __restrict__ wr = w_hh + (g * HIDD + u) * HIDD + 32 * kq;
#pragma unroll
        for (int j = 0; j < 4; ++j) {
            const int c0 = 8 * ((j + kq) & 3);
#pragma unroll
            for (int p = 0; p < 4; ++p) {
                const float f0 = wr[c0 + 2 * p];
                const float f1 = wr[c0 + 2 * p + 1];
                w2h[g][4 * j + p] = pack_f16(f0, f1);
            }
        }
    }
#pragma unroll
    for (int g = 0; g < 4; ++g)
#pragma unroll
        for (int k = 0; k < 16; ++k)
            asm volatile("" : "+v"(w2h[g][k]));   // no rematerialization

    if (tid < HIDD) {
        h_db[0][tid] = (_Float16)0.f;
        h_db[1][tid] = (_Float16)0.f;
    }
    float c = 0.f;
    float hreg[CH];
    float4 zcur[CH];
#pragma unroll
    for (int s = 0; s < CH; ++s) hreg[s] = 0.f;

    const float4* __restrict__ zx4 = (const float4*)zxT;
    __syncthreads();

    for (int tc = 0; tc < BSEQ; tc += CH) {
        // Batch-store previous chunk's h (one lane per unit, coalesced).
        if (writer && tc > 0) {
#pragma unroll
            for (int s = 0; s < CH; ++s)
                hs[(tc - CH + s) * HIDD + u] = hreg[s];
        }
        // This chunk's zx rows (one exposed stall per chunk at the first
        // in-chunk barrier).
#pragma unroll
        for (int s = 0; s < CH; ++s)
            zcur[s] = zx4[(tc + s) * HIDD + u];

#pragma unroll
        for (int s = 0; s < CH; ++s) {
            // tc multiple of CH (even) -> buffer parity is compile-time s&1.
            const uint4* __restrict__ rb =
                (const uint4*)(&h_db[s & 1][32 * kq]);   // 4 uint4 chunks
            const int wb = (s & 1) ^ 1;

            float z0 = 0.f, z1 = 0.f, z2 = 0.f, z3 = 0.f;
#pragma unroll
            for (int j = 0; j < 4; ++j) {
                const int cj = (j + kq) & 3;             // rotated chunk
                const uint4 hb = rb[cj];                 // ds_read_b128
                v2h hp[4];
                hp[0] = __builtin_bit_cast(v2h, hb.x);
                hp[1] = __builtin_bit_cast(v2h, hb.y);
                hp[2] = __builtin_bit_cast(v2h, hb.z);
                hp[3] = __builtin_bit_cast(v2h, hb.w);
#pragma unroll
                for (int p = 0; p < 4; ++p) {
                    z0 = __builtin_amdgcn_fdot2(hp[p], w2h[0][4 * j + p], z0, false);
                    z1 = __builtin_amdgcn_fdot2(hp[p], w2h[1][4 * j + p], z1, false);
                    z2 = __builtin_amdgcn_fdot2(hp[p], w2h[2][4 * j + p], z2, false);
                    z3 = __builtin_amdgcn_fdot2(hp[p], w2h[3][4 * j + p], z3, false);
                }
            }

            // Quad butterfly: all 4 lanes end with complete z per gate.
            z0 = DPP_ADD(z0, 0xB1); z0 = DPP_ADD(z0, 0x4E);
            z1 = DPP_ADD(z1, 0xB1); z1 = DPP_ADD(z1, 0x4E);
            z2 = DPP_ADD(z2, 0xB1); z2 = DPP_ADD(z2, 0x4E);
            z3 = DPP_ADD(z3, 0xB1); z3 = DPP_ADD(z3, 0x4E);

            const float4 zb = zcur[s];
            const float gi = fast_sigmoid(z0 + zb.x);
            const float gf = fast_sigmoid(z1 + zb.y);
            const float gg = fast_tanh   (z2 + zb.z);
            const float go = fast_sigmoid(z3 + zb.w);
            c = gf * c + gi * gg;                  // replicated x4: identical
            const float h = go * fast_tanh(c);
            hreg[s] = h;                           // fp32 for hs / FC
            if (writer) h_db[wb][u] = (_Float16)h; // f16 recurrent broadcast
            __syncthreads();                       // the one barrier per step
        }
    }
    if (writer) {
#pragma unroll
        for (int s = 0; s < CH; ++s)
            hs[(BSEQ - CH + s) * HIDD + u] = hreg[s];
    }
}

// ---------------------------------------------------------------------------
// Kernel 3: final FC. out[t][n] = dot(hs[t], w_fc[n]) + b_fc[n].
// ---------------------------------------------------------------------------
__global__ void fc_kernel(const float* __restrict__ hs,
                          const float* __restrict__ w_fc,
                          const float* __restrict__ b_fc,
                          float* __restrict__ out) {
    const int gid = blockIdx.x * blockDim.x + threadIdx.x;
    if (gid >= BSEQ * NTAR) return;
    const int n = gid & (NTAR - 1);
    const int t = gid >> 4;
    const float4* __restrict__ hr = (const float4*)(hs + t * HIDD);
    const float4* __restrict__ wr = (const float4*)(w_fc + n * HIDD);
    float acc = 0.f;
#pragma unroll
    for (int k = 0; k < HIDD / 4; ++k) {
        float4 h = hr[k];
        float4 wv = wr[k];
        acc += h.x * wv.x + h.y * wv.y + h.z * wv.z + h.w * wv.w;
    }
    out[gid] = acc + b_fc[n];
}

// ---------------------------------------------------------------------------
extern "C" void kernel_launch(void* const* d_in, const int* in_sizes, int n_in,
                              void* d_out, int out_size, void* d_ws, size_t ws_size,
                              hipStream_t stream) {
    const int*   x    = (const int*)d_in[0];
    const float* emb  = (const float*)d_in[1];
    const float* w_ih = (const float*)d_in[2];
    const float* w_hh = (const float*)d_in[3];
    const float* b_ih = (const float*)d_in[4];
    const float* b_hh = (const float*)d_in[5];
    const float* w_fc = (const float*)d_in[6];
    const float* b_fc = (const float*)d_in[7];
    float* out = (float*)d_out;

    // Workspace: zxT (4096*512 f32 = 8 MB) | hs (4096*128 f32 = 2 MB)
    float* zxT = (float*)d_ws;
    float* hs  = zxT + (size_t)BSEQ * G4;

    input_proj_kernel<<<BSEQ, G4, 0, stream>>>(x, emb, w_ih, b_ih, b_hh, zxT);
    lstm_seq_kernel<<<1, 512, 0, stream>>>(zxT, w_hh, hs);
    fc_kernel<<<(BSEQ * NTAR + 255) / 256, 256, 0, stream>>>(hs, w_fc, b_fc, out);
}

// Round 9
// 2366.887 us; speedup vs baseline: 1.3255x; 1.0305x over previous
//
#include <hip/hip_runtime.h>
#include <math.h>

#define EMBD 128
#define HIDD 128
#define NTAR 16
#define BSEQ 4096
#define G4   512
#define CH   8            // zx load / hs store batch (amortizes barrier vmcnt drain)

typedef _Float16 v2h __attribute__((ext_vector_type(2)));

// Quad-lane butterfly add (validated R5/R6/R8): 0xB1=[1,0,3,2], 0x4E=[2,3,0,1].
#define DPP_ADD(x, ctrl)                                                     \
    ((x) + __int_as_float(__builtin_amdgcn_update_dpp(                       \
               0, __float_as_int(x), (ctrl), 0xf, 0xf, true)))
// Quad-lane broadcast of lane g's value to all 4 quad lanes:
// ctrl = g|g<<2|g<<4|g<<6 -> 0x00 / 0x55 / 0xAA / 0xFF.
#define DPP_BCAST(x, ctrl)                                                   \
    (__int_as_float(__builtin_amdgcn_update_dpp(                             \
         0, __float_as_int(x), (ctrl), 0xf, 0xf, true)))

__device__ __forceinline__ float fast_tanh(float z) {
    return 1.f - 2.f * __builtin_amdgcn_rcpf(1.f + __expf(2.f * z));
}

// f32 pair -> packed f16 (RTZ), bit-cast to our v2h element type.
__device__ __forceinline__ v2h pack_f16(float f0, float f1) {
    return __builtin_bit_cast(v2h, __builtin_amdgcn_cvt_pkrtz(f0, f1));
}

// ---------------------------------------------------------------------------
// Kernel 1: input projection, transposed layout (fp32 — zx precision anchor).
// zxT[(t*128 + u)*4 + g] = dot(emb[x[t]], w_ih[g*128+u]) + b_ih + b_hh
// ---------------------------------------------------------------------------
__global__ void input_proj_kernel(const int* __restrict__ x,
                                  const float* __restrict__ emb,
                                  const float* __restrict__ w_ih,
                                  const float* __restrict__ b_ih,
                                  const float* __restrict__ b_hh,
                                  float* __restrict__ zxT) {
    const int t = blockIdx.x;
    const int j = threadIdx.x;            // 0..511
    const int u = j >> 2;
    const int g = j & 3;
    const int row = g * HIDD + u;
    const int idx = x[t];
    const float4* __restrict__ er = (const float4*)(emb + (long long)idx * EMBD);
    const float4* __restrict__ wr = (const float4*)(w_ih + row * EMBD);
    float acc = 0.f;
#pragma unroll
    for (int k = 0; k < EMBD / 4; ++k) {
        float4 e = er[k];
        float4 w = wr[k];
        acc += e.x * w.x + e.y * w.y + e.z * w.z + e.w * w.w;
    }
    zxT[(t * HIDD + u) * 4 + g] = acc + b_ih[row] + b_hh[row];
}

// ---------------------------------------------------------------------------
// Kernel 2: sequential LSTM. 512 threads (8 waves, 2/SIMD), one barrier/step.
//
// R8 post-mortem: VALU-issue-bound at ~74% (v_dot2_f32_f16 is HALF-rate —
// 4 cyc/wave64, same MAC rate as fp32 fma; the f16 win is fewer LDS bytes,
// not MAC speed). R9 trims the non-MAC issue:
//  - transcendental dedup: lane kq computes ONLY gate kq's activation
//    (z-select via 3 cndmask, form via hoisted lane-constant mA/cA/cB),
//    then 4 quad_perm DPP broadcasts distribute the acts. 2 exp + 2 rcp
//    per thread instead of 5 + 5. Numerically identical to R8.
//  - zx as per-lane scalars: index t*512 + wv*64 + l is consecutive across
//    the wave (coalesced 256 B loads), no float4 select.
//  - zfut chunk-ahead prefetch: the vm drain at each barrier only sees
//    loads issued a full chunk (~10k cyc) earlier.
//  - split dot accumulators (2/gate) to halve the fdot2 chain depth.
// ---------------------------------------------------------------------------
__global__ __launch_bounds__(512, 2)
void lstm_seq_kernel(const float* __restrict__ zxT,
                     const float* __restrict__ w_hh,
                     float* __restrict__ hs) {
    __shared__ __align__(16) _Float16 h_db[2][HIDD];

    const int tid = threadIdx.x;
    const int l   = tid & 63;
    const int wv  = tid >> 6;
    const int kq  = l & 3;               // k-quarter AND this lane's gate
    const int us  = l >> 2;              // unit-sub 0..15
    const int u   = wv * 16 + us;        // hidden unit 0..127
    const bool writer = (kq == 0);

    // Lane-constant activation coefficients (hoisted predication):
    // sigmoid(z) = rcp(1+exp(-z));  tanh(z) = 1 - 2*rcp(1+exp(2z)).
    const float mA = (kq == 2) ? 2.f : -1.f;   // exp argument multiplier
    const float cA = (kq == 2) ? -2.f : 1.f;   // act = cA*r + cB
    const float cB = (kq == 2) ? 1.f : 0.f;

    // Weights as half2, chunk-rotated to match the h read order below:
    // w2h[g][4*j + p] covers cols 32kq + 8*((j+kq)&3) + 2p .. +1.
    v2h w2h[4][16];
#pragma unroll
    for (int g = 0; g < 4; ++g) {
        const float* __restrict__ wr = w_hh + (g * HIDD + u) * HIDD + 32 * kq;
#pragma unroll
        for (int j = 0; j < 4; ++j) {
            const int c0 = 8 * ((j + kq) & 3);
#pragma unroll
            for (int p = 0; p < 4; ++p) {
                const float f0 = wr[c0 + 2 * p];
                const float f1 = wr[c0 + 2 * p + 1];
                w2h[g][4 * j + p] = pack_f16(f0, f1);
            }
        }
    }
#pragma unroll
    for (int g = 0; g < 4; ++g)
#pragma unroll
        for (int k = 0; k < 16; ++k)
            asm volatile("" : "+v"(w2h[g][k]));   // no rematerialization

    if (tid < HIDD) {
        h_db[0][tid] = (_Float16)0.f;
        h_db[1][tid] = (_Float16)0.f;
    }
    float c = 0.f;
    float hreg[CH];
    float zcur[CH], zfut[CH];
    // Per-lane zx scalar stream: index t*512 + wv*64 + l (wave-consecutive).
    const int zoff = wv * 64 + l;
#pragma unroll
    for (int s = 0; s < CH; ++s) {
        zcur[s] = zxT[s * G4 + zoff];
        hreg[s] = 0.f;
    }
    __syncthreads();

    for (int tc = 0; tc < BSEQ; tc += CH) {
        // Batch-store previous chunk's h (one lane per unit, coalesced).
        if (writer && tc > 0) {
#pragma unroll
            for (int s = 0; s < CH; ++s)
                hs[(tc - CH + s) * HIDD + u] = hreg[s];
        }
        // Prefetch NEXT chunk's zx scalars (a full chunk of latency).
        {
            const int tn = (tc + CH < BSEQ) ? (tc + CH) : (BSEQ - CH);
#pragma unroll
            for (int s = 0; s < CH; ++s)
                zfut[s] = zxT[(tn + s) * G4 + zoff];
        }

#pragma unroll
        for (int s = 0; s < CH; ++s) {
            // tc multiple of CH (even) -> buffer parity is compile-time s&1.
            const uint4* __restrict__ rb =
                (const uint4*)(&h_db[s & 1][32 * kq]);   // 4 uint4 chunks
            const int wb = (s & 1) ^ 1;

            // Split accumulators: halve the fdot2 dependence depth.
            float z0a = 0.f, z1a = 0.f, z2a = 0.f, z3a = 0.f;
            float z0b = 0.f, z1b = 0.f, z2b = 0.f, z3b = 0.f;
#pragma unroll
            for (int j = 0; j < 4; ++j) {
                const int cj = (j + kq) & 3;             // rotated chunk
                const uint4 hb = rb[cj];                 // ds_read_b128
                v2h hp[4];
                hp[0] = __builtin_bit_cast(v2h, hb.x);
                hp[1] = __builtin_bit_cast(v2h, hb.y);
                hp[2] = __builtin_bit_cast(v2h, hb.z);
                hp[3] = __builtin_bit_cast(v2h, hb.w);
                if (j < 2) {
#pragma unroll
                    for (int p = 0; p < 4; ++p) {
                        z0a = __builtin_amdgcn_fdot2(hp[p], w2h[0][4 * j + p], z0a, false);
                        z1a = __builtin_amdgcn_fdot2(hp[p], w2h[1][4 * j + p], z1a, false);
                        z2a = __builtin_amdgcn_fdot2(hp[p], w2h[2][4 * j + p], z2a, false);
                        z3a = __builtin_amdgcn_fdot2(hp[p], w2h[3][4 * j + p], z3a, false);
                    }
                } else {
#pragma unroll
                    for (int p = 0; p < 4; ++p) {
                        z0b = __builtin_amdgcn_fdot2(hp[p], w2h[0][4 * j + p], z0b, false);
                        z1b = __builtin_amdgcn_fdot2(hp[p], w2h[1][4 * j + p], z1b, false);
                        z2b = __builtin_amdgcn_fdot2(hp[p], w2h[2][4 * j + p], z2b, false);
                        z3b = __builtin_amdgcn_fdot2(hp[p], w2h[3][4 * j + p], z3b, false);
                    }
                }
            }
            float z0 = z0a + z0b, z1 = z1a + z1b;
            float z2 = z2a + z2b, z3 = z3a + z3b;

            // Quad butterfly: all lanes get complete dot sums per gate.
            z0 = DPP_ADD(z0, 0xB1); z0 = DPP_ADD(z0, 0x4E);
            z1 = DPP_ADD(z1, 0xB1); z1 = DPP_ADD(z1, 0x4E);
            z2 = DPP_ADD(z2, 0xB1); z2 = DPP_ADD(z2, 0x4E);
            z3 = DPP_ADD(z3, 0xB1); z3 = DPP_ADD(z3, 0x4E);

            // Lane kq finishes ONLY gate kq: select z, add own zx scalar,
            // one predicated-by-constants activation (1 exp + 1 rcp).
            float zs = z0;
            zs = (kq == 1) ? z1 : zs;
            zs = (kq == 2) ? z2 : zs;
            zs = (kq == 3) ? z3 : zs;
            const float zfull = zs + zcur[s];
            const float r   = __builtin_amdgcn_rcpf(1.f + __expf(mA * zfull));
            const float act = fmaf(cA, r, cB);

            // Broadcast the 4 acts across the quad (no cndmask needed).
            const float gi = DPP_BCAST(act, 0x00);
            const float gf = DPP_BCAST(act, 0x55);
            const float gg = DPP_BCAST(act, 0xAA);
            const float go = DPP_BCAST(act, 0xFF);

            c = gf * c + gi * gg;                  // replicated x4: identical
            const float h = go * fast_tanh(c);
            hreg[s] = h;                           // fp32 for hs / FC
            if (writer) h_db[wb][u] = (_Float16)h; // f16 recurrent broadcast
            __syncthreads();                       // the one barrier per step
        }
#pragma unroll
        for (int s = 0; s < CH; ++s) zcur[s] = zfut[s];
    }
    if (writer) {
#pragma unroll
        for (int s = 0; s < CH; ++s)
            hs[(BSEQ - CH + s) * HIDD + u] = hreg[s];
    }
}

// ---------------------------------------------------------------------------
// Kernel 3: final FC. out[t][n] = dot(hs[t], w_fc[n]) + b_fc[n].
// ---------------------------------------------------------------------------
__global__ void fc_kernel(const float* __restrict__ hs,
                          const float* __restrict__ w_fc,
                          const float* __restrict__ b_fc,
                          float* __restrict__ out) {
    const int gid = blockIdx.x * blockDim.x + threadIdx.x;
    if (gid >= BSEQ * NTAR) return;
    const int n = gid & (NTAR - 1);
    const int t = gid >> 4;
    const float4* __restrict__ hr = (const float4*)(hs + t * HIDD);
    const float4* __restrict__ wr = (const float4*)(w_fc + n * HIDD);
    float acc = 0.f;
#pragma unroll
    for (int k = 0; k < HIDD / 4; ++k) {
        float4 h = hr[k];
        float4 wv = wr[k];
        acc += h.x * wv.x + h.y * wv.y + h.z * wv.z + h.w * wv.w;
    }
    out[gid] = acc + b_fc[n];
}

// ---------------------------------------------------------------------------
extern "C" void kernel_launch(void* const* d_in, const int* in_sizes, int n_in,
                              void* d_out, int out_size, void* d_ws, size_t ws_size,
                              hipStream_t stream) {
    const int*   x    = (const int*)d_in[0];
    const float* emb  = (const float*)d_in[1];
    const float* w_ih = (const float*)d_in[2];
    const float* w_hh = (const float*)d_in[3];
    const float* b_ih = (const float*)d_in[4];
    const float* b_hh = (const float*)d_in[5];
    const float* w_fc = (const float*)d_in[6];
    const float* b_fc = (const float*)d_in[7];
    float* out = (float*)d_out;

    // Workspace: zxT (4096*512 f32 = 8 MB) | hs (4096*128 f32 = 2 MB)
    float* zxT = (float*)d_ws;
    float* hs  = zxT + (size_t)BSEQ * G4;

    input_proj_kernel<<<BSEQ, G4, 0, stream>>>(x, emb, w_ih, b_ih, b_hh, zxT);
    lstm_seq_kernel<<<1, 512, 0, stream>>>(zxT, w_hh, hs);
    fc_kernel<<<(BSEQ * NTAR + 255) / 256, 256, 0, stream>>>(hs, w_fc, b_fc, out);
}